// Round 4
// baseline (71.279 us; speedup 1.0000x reference)
//
#include <hip/hip_runtime.h>
#include <hip/hip_bf16.h>

#define M_DIM 4096
#define N_DIM 4096
#define K_DIM 1024
#define NT (K_DIM / 64)   // 16 K-tiles of BK=64

typedef short short8 __attribute__((ext_vector_type(8)));
typedef unsigned short ushort8 __attribute__((ext_vector_type(8)));
typedef float f32x4 __attribute__((ext_vector_type(4)));

// fp32 -> bf16 round-to-nearest-even (bias-free over the K-sum)
__device__ __forceinline__ unsigned short f2bf_rne(float f) {
    union { float f; unsigned u; } v;
    v.f = f;
    unsigned u = v.u;
    u += 0x7FFFu + ((u >> 16) & 1u);
    return (unsigned short)(u >> 16);
}

// packed fp32x2 -> bf16x2, hardware RNE (no builtin on gfx950 -> inline asm)
__device__ __forceinline__ unsigned cvtpk(float lo, float hi) {
    unsigned r;
    asm("v_cvt_pk_bf16_f32 %0, %1, %2" : "=v"(r) : "v"(lo), "v"(hi));
    return r;
}

// ---- B transpose+convert: K x N fp32 -> Bt: N x K bf16 (B-only now) ----
__global__ __launch_bounds__(256) void cvtBT_kernel(const float* __restrict__ B,
                                                    unsigned short* __restrict__ Bt) {
    __shared__ unsigned short tile[32][33];
    int bx = blockIdx.x & 127, by = blockIdx.x >> 7;    // 128 x 32 blocks
    int x = threadIdx.x & 31, y = threadIdx.x >> 5;     // 32 x 8
    int n0 = bx * 32, k0 = by * 32;
#pragma unroll
    for (int j = 0; j < 4; ++j)
        tile[y + j * 8][x] = f2bf_rne(B[(size_t)(k0 + y + j * 8) * N_DIM + n0 + x]);
    __syncthreads();
#pragma unroll
    for (int j = 0; j < 4; ++j)
        Bt[(size_t)(n0 + y + j * 8) * K_DIM + k0 + x] = tile[x][y + j * 8];
}

// ---- 256x256x64 GEMM: C fp32 = A(fp32 MxK, cvt in-kernel) * Bt(bf16 NxK direct) ----
// 8 waves (2Mx4N), per-wave 128x64 = acc[8][4].
// A: reg-staged fp32 -> cvt_pk -> swizzled ds_write into 2x32KB dbuf; 1 barrier/tile.
// B: fragments loaded straight from global (coalesced 16B/lane, L1/L2-hot).
__global__ __launch_bounds__(512, 2) void gemm8_kernel(const float* __restrict__ A,
                                                       const unsigned short* __restrict__ Bt,
                                                       float* __restrict__ C) {
    __shared__ __align__(16) unsigned short sA[2][256 * 64];   // 64 KiB total

    // XCD-aware bijective swizzle: 256 blocks, 8 XCDs; same-XCD blocks share tm
    // (2 A-panels = 2MB fp32, L2-resident per XCD).
    int bid = blockIdx.x;
    int xcd = bid & 7, ii = bid >> 3;
    int tm = xcd * 2 + (ii & 1);
    int tn = ii >> 1;
    int bM = tm * 256, bN = tn * 256;

    int tid = threadIdx.x;
    int wid = tid >> 6, lane = tid & 63;
    int wm = wid >> 2, wn = wid & 3;

    // ---- A staging map: flat 16B chunk c = i*8192 + tid*16 over the 64KB fp32 tile
    // row = i*32 + (tid>>4), k-floats (tid&15)*4..+3  -> fully coalesced (4x256B/instr)
    int rowg = tid >> 4;            // 0..31
    int kf = tid & 15;              // 16B chunk within the row's 256B k-slice
    const float* gAs = A + (size_t)(bM + rowg) * K_DIM + kf * 4;
    // LDS write: slot s=kf>>1, half=kf&1, swizzled s' = s ^ (row&7); row&7 == rowg&7
    int wbase = rowg * 128 + ((kf >> 1) ^ (rowg & 7)) * 16 + (kf & 1) * 8;

    // ---- B direct-fragment base: row bN + wn*64 + n*16 + (lane&15), 16B at k-slot
    const unsigned short* gBs =
        Bt + (size_t)(bN + wn * 64 + (lane & 15)) * K_DIM + (lane >> 4) * 8;

    // ---- A fragment reads from LDS
    int rA = wm * 128 + (lane & 15);
    int rslot = lane >> 4;
    int l7 = lane & 7;
#define LDA(buf, m, k) \
    (*(const short8*)&sA[buf][(rA + (m) * 16) * 64 + ((((k) * 4 + rslot) ^ l7) * 8)])

    f32x4 acc[8][4];
#pragma unroll
    for (int m = 0; m < 8; ++m)
#pragma unroll
        for (int n = 0; n < 4; ++n)
            acc[m][n] = (f32x4){0.f, 0.f, 0.f, 0.f};

    float4 st[4];
    short8 avA[2][2], avB[2][2];

#define ALOAD(i, kt) (*(const float4*)(gAs + (size_t)(i) * 32 * K_DIM + (size_t)(kt) * 64))
#define AWRT(NB, i, j)                                                                  \
    *(uint2*)((char*)&sA[NB][0] + wbase + ((i) + (j)) * 4096) =                         \
        (uint2){cvtpk(st[j].x, st[j].y), cvtpk(st[j].z, st[j].w)};

#define LDAV(AV, BUF, MB)                                                               \
    _Pragma("unroll") for (int m2 = 0; m2 < 2; ++m2)                                    \
        _Pragma("unroll") for (int k = 0; k < 2; ++k)                                   \
            AV[m2][k] = LDA(BUF, (MB) + m2, k);

    // k-outer: 8 independent MFMAs between dependent writes to each acc
#define MFMA8(AV, BV, MB)                                                               \
    __builtin_amdgcn_s_setprio(1);                                                      \
    _Pragma("unroll") for (int k = 0; k < 2; ++k)                                       \
        _Pragma("unroll") for (int m2 = 0; m2 < 2; ++m2)                                \
            _Pragma("unroll") for (int n = 0; n < 4; ++n)                               \
                acc[(MB) + m2][n] = __builtin_amdgcn_mfma_f32_16x16x32_bf16(            \
                    AV[m2][k], BV[n][k], acc[(MB) + m2][n], 0, 0, 0);                   \
    __builtin_amdgcn_s_setprio(0);

    // one K-tile: reads buf CB, stages tile t+1 into buf NB (compile-time 0/1)
#define TILE(t, CB, NB)                                                                 \
    {                                                                                   \
        const bool hn = (t) + 1 < NT;                                                   \
        if (hn) {                                                                       \
            _Pragma("unroll") for (int j = 0; j < 4; ++j) st[j] = ALOAD(j, (t) + 1);    \
        }                                                                               \
        short8 bv[4][2];                                                                \
        _Pragma("unroll") for (int n = 0; n < 4; ++n)                                   \
            _Pragma("unroll") for (int k = 0; k < 2; ++k)                               \
                bv[n][k] = *(const short8*)(gBs + (size_t)n * 16 * K_DIM +              \
                                            (size_t)(t) * 64 + k * 32);                 \
        LDAV(avA, CB, 0)                                                                \
        MFMA8(avA, bv, 0)                                                               \
        LDAV(avB, CB, 2)                                                                \
        MFMA8(avB, bv, 2)                                                               \
        LDAV(avA, CB, 4)                                                                \
        if (hn) {                                                                       \
            AWRT(NB, 0, 0) AWRT(NB, 0, 1) AWRT(NB, 0, 2) AWRT(NB, 0, 3)                 \
            _Pragma("unroll") for (int j = 0; j < 4; ++j) st[j] = ALOAD(4 + j, (t) + 1);\
        }                                                                               \
        MFMA8(avA, bv, 4)                                                               \
        LDAV(avB, CB, 6)                                                                \
        if (hn) { AWRT(NB, 4, 0) AWRT(NB, 4, 1) AWRT(NB, 4, 2) AWRT(NB, 4, 3) }         \
        MFMA8(avB, bv, 6)                                                               \
        asm volatile("s_waitcnt lgkmcnt(0)" ::: "memory");                              \
        __builtin_amdgcn_sched_barrier(0);                                              \
        __builtin_amdgcn_s_barrier();                                                   \
    }

    // ---- prologue: stage tile 0 into buf 0 ----
#pragma unroll
    for (int j = 0; j < 4; ++j) st[j] = ALOAD(j, 0);
    AWRT(0, 0, 0) AWRT(0, 0, 1) AWRT(0, 0, 2) AWRT(0, 0, 3)
#pragma unroll
    for (int j = 0; j < 4; ++j) st[j] = ALOAD(4 + j, 0);
    AWRT(0, 4, 0) AWRT(0, 4, 1) AWRT(0, 4, 2) AWRT(0, 4, 3)
    asm volatile("s_waitcnt lgkmcnt(0)" ::: "memory");
    __builtin_amdgcn_sched_barrier(0);
    __builtin_amdgcn_s_barrier();

    for (int t = 0; t < NT; t += 2) {
        TILE(t, 0, 1)
        TILE(t + 1, 1, 0)
    }

    // ---- epilogue: C/D layout col=lane&15, row=(lane>>4)*4+r ----
    size_t crow = (size_t)bM + wm * 128 + ((lane >> 4) << 2);
    int ccol = bN + wn * 64 + (lane & 15);
#pragma unroll
    for (int m = 0; m < 8; ++m)
#pragma unroll
        for (int n = 0; n < 4; ++n)
#pragma unroll
            for (int r = 0; r < 4; ++r)
                C[(crow + m * 16 + r) * N_DIM + ccol + n * 16] = acc[m][n][r];
#undef LDA
#undef ALOAD
#undef AWRT
#undef LDAV
#undef MFMA8
#undef TILE
}

// ---- fallback: plain fp32 tiled GEMM (only if ws too small; exact) ----
__global__ __launch_bounds__(256) void sgemm_fb(const float* __restrict__ A,
                                                const float* __restrict__ B,
                                                float* __restrict__ C) {
    __shared__ float sA[64][17];
    __shared__ float sB[16][65];
    int tx = threadIdx.x, ty = threadIdx.y;
    int bM = blockIdx.y * 64, bN = blockIdx.x * 64;
    int t = ty * 16 + tx;
    float acc[4][4] = {};
    for (int k0 = 0; k0 < K_DIM; k0 += 16) {
        __syncthreads();
#pragma unroll
        for (int e = 0; e < 4; ++e) {
            int idx = t * 4 + e;
            int r = idx >> 4, c = idx & 15;
            sA[r][c] = A[(size_t)(bM + r) * K_DIM + k0 + c];
            int r2 = idx >> 6, c2 = idx & 63;
            sB[r2][c2] = B[(size_t)(k0 + r2) * N_DIM + bN + c2];
        }
        __syncthreads();
#pragma unroll
        for (int k = 0; k < 16; ++k) {
            float ar[4], br[4];
#pragma unroll
            for (int q = 0; q < 4; ++q) { ar[q] = sA[ty * 4 + q][k]; br[q] = sB[k][tx * 4 + q]; }
#pragma unroll
            for (int q = 0; q < 4; ++q)
#pragma unroll
                for (int w = 0; w < 4; ++w)
                    acc[q][w] += ar[q] * br[w];
        }
    }
#pragma unroll
    for (int q = 0; q < 4; ++q)
#pragma unroll
        for (int w = 0; w < 4; ++w)
            C[(size_t)(bM + ty * 4 + q) * N_DIM + bN + tx * 4 + w] = acc[q][w];
}

extern "C" void kernel_launch(void* const* d_in, const int* in_sizes, int n_in,
                              void* d_out, int out_size, void* d_ws, size_t ws_size,
                              hipStream_t stream) {
    const float* A = (const float*)d_in[0];
    const float* B = (const float*)d_in[1];
    float* C = (float*)d_out;

    size_t needB = (size_t)K_DIM * N_DIM * sizeof(unsigned short);

    if (ws_size >= needB) {
        unsigned short* Bw = (unsigned short*)d_ws;
        cvtBT_kernel<<<4096, 256, 0, stream>>>(B, Bw);
        gemm8_kernel<<<(M_DIM / 256) * (N_DIM / 256), 512, 0, stream>>>(A, Bw, C);
    } else {
        sgemm_fb<<<dim3(N_DIM / 64, M_DIM / 64), dim3(16, 16), 0, stream>>>(A, B, C);
    }
}